// Round 8
// baseline (1454.194 us; speedup 1.0000x reference)
//
#include <hip/hip_runtime.h>
#include <hip/hip_bf16.h>

#define BSZ 16
#define SEQ 512
#define DIM 512
#define NH 8
#define DK 64
#define NROWS (BSZ*SEQ)   // 8192
#define DFF2 2048

typedef unsigned short u16;
typedef u16   u16x8 __attribute__((ext_vector_type(8)));
typedef short s16x8 __attribute__((ext_vector_type(8)));
typedef float f32x4 __attribute__((ext_vector_type(4)));

__device__ __forceinline__ u16 f2b(float x) {
    union { float f; unsigned int u; } c; c.f = x;
    unsigned int r = c.u + 0x7fff + ((c.u >> 16) & 1);   // RNE
    return (u16)(r >> 16);
}
__device__ __forceinline__ float b2f(u16 u) {
    union { unsigned int i; float f; } c; c.i = ((unsigned int)u) << 16; return c.f;
}

// async global->LDS, 16B per lane. LDS dest = wave-uniform base + lane*16.
__device__ __forceinline__ void gld16(const u16* g, u16* l) {
    __builtin_amdgcn_global_load_lds(
        (const __attribute__((address_space(1))) unsigned int*)(unsigned long long)g,
        (__attribute__((address_space(3))) unsigned int*)(unsigned int)(unsigned long long)l,
        16, 0, 0);
}

// ---- cast fp32 -> bf16 ----
__global__ __launch_bounds__(256) void cast_f2b4(const float* __restrict__ in,
                                                 u16* __restrict__ out, int n4) {
    int i = blockIdx.x * 256 + threadIdx.x;
    if (i >= n4) return;
    float4 v = ((const float4*)in)[i];
    ushort4 o; o.x = f2b(v.x); o.y = f2b(v.y); o.z = f2b(v.z); o.w = f2b(v.w);
    ((ushort4*)out)[i] = o;
}

// ---- transpose + cast weights: dest[z][N][K](bf16) from W[layer0+z*lstride][K][N](fp32) ----
__global__ __launch_bounds__(256) void transpose_cast(
    const float* __restrict__ W, u16* __restrict__ WT,
    int K, int N, int layer0, int lstride, size_t dstride)
{
    __shared__ float t[32][33];
    int z = blockIdx.z;
    const float* Wz = W + (size_t)(layer0 + z * lstride) * K * N;
    u16* WTz = WT + (size_t)z * dstride;
    int k0 = blockIdx.x * 32, n0 = blockIdx.y * 32;
    int tx = threadIdx.x & 31, ty = threadIdx.x >> 5;
    for (int i = ty; i < 32; i += 8) t[i][tx] = Wz[(size_t)(k0 + i) * N + n0 + tx];
    __syncthreads();
    for (int i = ty; i < 32; i += 8) WTz[(size_t)(n0 + i) * K + k0 + tx] = f2b(t[tx][i]);
}

// ---- m97-style MFMA GEMM. C[M,N] = A[M,K] @ WT[N,K]^T + bias. 128x128, BK=32. ----
// SPLIT: columns >= nsplit use Av/bias2/C2 (for fused q|v with different A streams).
template<int WRITE_BF16, int RELU, int ACCUM, int SPLIT>
__global__ __launch_bounds__(256) void gemm2(
    const u16* __restrict__ Aq, const u16* __restrict__ Av,
    const u16* __restrict__ WT,
    const float* __restrict__ bias1, const float* __restrict__ bias2,
    void* __restrict__ C1, void* __restrict__ C2,
    int K, int lda, int ldw, int ldc, int nsplit)
{
    __shared__ __attribute__((aligned(16))) u16 As[128 * 32];
    __shared__ __attribute__((aligned(16))) u16 Bs[128 * 32];
    int tid = threadIdx.x;
    int wave = tid >> 6, lane = tid & 63;
    int quad = lane >> 4, l16 = lane & 15;
    int n0 = blockIdx.x * 128, m0 = blockIdx.y * 128;
    int wrow = (wave & 1) * 64, wcol = (wave >> 1) * 64;
    bool isv = SPLIT && (n0 >= nsplit);
    const u16* A = isv ? Av : Aq;

    int sr = wave * 32 + (lane >> 2);
    int sc = (lane & 3) * 8;
    const u16* gA0 = A  + (size_t)(m0 + sr) * lda + sc;
    const u16* gA1 = gA0 + (size_t)16 * lda;
    const u16* gB0 = WT + (size_t)(n0 + sr) * ldw + sc;
    const u16* gB1 = gB0 + (size_t)16 * ldw;
    u16* lA0 = As + (wave * 32) * 32;
    u16* lA1 = As + (wave * 32 + 16) * 32;
    u16* lB0 = Bs + (wave * 32) * 32;
    u16* lB1 = Bs + (wave * 32 + 16) * 32;

    f32x4 acc[4][4];
    #pragma unroll
    for (int i = 0; i < 4; i++)
        #pragma unroll
        for (int j = 0; j < 4; j++) acc[i][j] = (f32x4){0.f, 0.f, 0.f, 0.f};

    for (int k0 = 0; k0 < K; k0 += 32) {
        __syncthreads();
        gld16(gA0 + k0, lA0);
        gld16(gA1 + k0, lA1);
        gld16(gB0 + k0, lB0);
        gld16(gB1 + k0, lB1);
        __syncthreads();

        s16x8 af[4], bf[4];
        #pragma unroll
        for (int i = 0; i < 4; i++) {
            af[i] = *(s16x8*)&As[(wrow + i * 16 + l16) * 32 + quad * 8];
            bf[i] = *(s16x8*)&Bs[(wcol + i * 16 + l16) * 32 + quad * 8];
        }
        #pragma unroll
        for (int mi = 0; mi < 4; mi++)
            #pragma unroll
            for (int ni = 0; ni < 4; ni++)
                acc[mi][ni] = __builtin_amdgcn_mfma_f32_16x16x32_bf16(
                    af[mi], bf[ni], acc[mi][ni], 0, 0, 0);
    }

    const float* bias = isv ? bias2 : bias1;
    void* C = isv ? C2 : C1;
    int nb = n0 - (isv ? nsplit : 0);
    #pragma unroll
    for (int ni = 0; ni < 4; ni++) {
        int cn = nb + wcol + ni * 16 + l16;
        float bb = bias ? bias[cn] : 0.f;
        #pragma unroll
        for (int mi = 0; mi < 4; mi++) {
            int cm = m0 + wrow + mi * 16 + quad * 4;
            #pragma unroll
            for (int r = 0; r < 4; r++) {
                size_t off = (size_t)(cm + r) * ldc + cn;
                float v = acc[mi][ni][r] + bb;
                if (ACCUM) v += ((float*)C)[off];
                if (RELU) v = fmaxf(v, 0.f);
                if (WRITE_BF16) ((u16*)C)[off] = f2b(v);
                else            ((float*)C)[off] = v;
            }
        }
    }
}

// ---- rmask init for all 6 layers: [l][b][h], shared heads = 1, routed = 0 ----
__global__ void init_rmask6(float* __restrict__ r) {
    int t = blockIdx.x * 256 + threadIdx.x;
    if (t < 6 * 128) r[t] = ((t & 7) < 2) ? 1.0f : 0.0f;
}

// ---- router, wave-per-row: 64 lanes x 8 dims; butterfly reduce; lane0 top-2 ----
__global__ __launch_bounds__(256) void router_kernel(
    const u16* __restrict__ qlin, const float* __restrict__ wg,
    float* __restrict__ rmask)
{
    __shared__ float s_wg[DIM * 6];
    int tid = threadIdx.x;
    for (int i = tid; i < DIM * 6; i += 256) s_wg[i] = wg[i];
    __syncthreads();
    int wave = tid >> 6, lane = tid & 63;
    int row = blockIdx.x * 4 + wave;
    u16x8 v = *(const u16x8*)(qlin + (size_t)row * DIM + lane * 8);
    float lg[6] = {0, 0, 0, 0, 0, 0};
    #pragma unroll
    for (int j = 0; j < 8; j++) {
        float x = b2f(v[j]);
        #pragma unroll
        for (int r = 0; r < 6; r++) lg[r] += x * s_wg[(lane * 8 + j) * 6 + r];
    }
    #pragma unroll
    for (int r = 0; r < 6; r++) {
        float t = lg[r];
        #pragma unroll
        for (int o = 1; o < 64; o <<= 1) t += __shfl_xor(t, o);
        lg[r] = t;
    }
    if (lane == 0) {
        float m = lg[0];
        #pragma unroll
        for (int r = 1; r < 6; r++) m = fmaxf(m, lg[r]);
        float s = 0.f;
        #pragma unroll
        for (int r = 0; r < 6; r++) { lg[r] = __expf(lg[r] - m); s += lg[r]; }
        float inv = 1.0f / s;
        #pragma unroll
        for (int r = 0; r < 6; r++) lg[r] *= inv;
        int i1 = 0; float v1 = lg[0];
        #pragma unroll
        for (int r = 1; r < 6; r++) if (lg[r] > v1) { v1 = lg[r]; i1 = r; }
        int i2 = -1; float v2 = -1.f;
        #pragma unroll
        for (int r = 0; r < 6; r++) if (r != i1 && lg[r] > v2) { v2 = lg[r]; i2 = r; }
        int b = row >> 9;
        atomicAdd(&rmask[b * 8 + 2 + i1], v1 * (1.0f / (float)SEQ));
        atomicAdd(&rmask[b * 8 + 2 + i2], v2 * (1.0f / (float)SEQ));
    }
}

// ---- per-layer V transpose: vT[b][h][d][j] from v[(b,j)][h*64+d] ----
__global__ __launch_bounds__(256) void transpose_v(
    const u16* __restrict__ v, u16* __restrict__ vT)
{
    __shared__ u16 t[64][72];
    int jt = blockIdx.x, bh = blockIdx.y;
    int b = bh >> 3, h = bh & 7;
    int tid = threadIdx.x;
    int lr = tid >> 2, lc = (tid & 3) * 16;
    const u16* src = v + (size_t)(b * SEQ + jt * 64 + lr) * DIM + h * DK + lc;
    *(u16x8*)&t[lr][lc]     = *(const u16x8*)src;
    *(u16x8*)&t[lr][lc + 8] = *(const u16x8*)(src + 8);
    __syncthreads();
    u16x8 o0, o1;
    #pragma unroll
    for (int i = 0; i < 8; i++) o0[i] = t[lc + i][lr];
    #pragma unroll
    for (int i = 0; i < 8; i++) o1[i] = t[lc + 8 + i][lr];
    u16* dst = vT + ((size_t)bh * DK + lr) * SEQ + jt * 64 + lc;
    *(u16x8*)dst       = o0;
    *(u16x8*)(dst + 8) = o1;
}

// ---- MFMA flash attention. Q/K from qlin16, V from vT (pre-transposed). ----
__global__ __launch_bounds__(256) void attn_flash(
    const u16* __restrict__ qlin, const u16* __restrict__ vT,
    const float* __restrict__ rmask, u16* __restrict__ ctx, int mask_flag)
{
    __shared__ u16 s_q [64][72];
    __shared__ u16 s_k [64][72];
    __shared__ u16 s_vt[64][72];   // [d][j]
    __shared__ u16 s_p [64][72];
    int qt = blockIdx.x, h = blockIdx.y, b = blockIdx.z;
    int tid = threadIdx.x;
    int wave = tid >> 6, lane = tid & 63;
    int quad = lane >> 4, l16 = lane & 15;
    int lr = tid >> 2, lc = (tid & 3) * 16;

    {
        const u16* src = qlin + (size_t)(b * SEQ + qt * 64 + lr) * DIM + h * DK + lc;
        *(u16x8*)&s_q[lr][lc]     = *(const u16x8*)src;
        *(u16x8*)&s_q[lr][lc + 8] = *(const u16x8*)(src + 8);
    }

    f32x4 acc_o[4];
    #pragma unroll
    for (int i = 0; i < 4; i++) acc_o[i] = (f32x4){0.f, 0.f, 0.f, 0.f};
    float m_i[4] = {-1e30f, -1e30f, -1e30f, -1e30f};
    float l_i[4] = {0.f, 0.f, 0.f, 0.f};

    for (int jt = 0; jt <= qt; jt++) {
        const u16* ksrc = qlin + (size_t)(b * SEQ + jt * 64 + lr) * DIM + h * DK + lc;
        const u16* vtsrc = vT + ((size_t)(b * NH + h) * DK + lr) * SEQ + jt * 64 + lc;
        u16x8 k0 = *(const u16x8*)ksrc,  k1 = *(const u16x8*)(ksrc + 8);
        u16x8 v0 = *(const u16x8*)vtsrc, v1 = *(const u16x8*)(vtsrc + 8);
        __syncthreads();
        *(u16x8*)&s_k[lr][lc]      = k0;
        *(u16x8*)&s_k[lr][lc + 8]  = k1;
        *(u16x8*)&s_vt[lr][lc]     = v0;
        *(u16x8*)&s_vt[lr][lc + 8] = v1;
        __syncthreads();

        f32x4 acc_s[4];
        #pragma unroll
        for (int i = 0; i < 4; i++) acc_s[i] = (f32x4){0.f, 0.f, 0.f, 0.f};
        #pragma unroll
        for (int ks = 0; ks < 2; ks++) {
            s16x8 a = *(s16x8*)&s_q[wave * 16 + l16][ks * 32 + quad * 8];
            #pragma unroll
            for (int nf = 0; nf < 4; nf++) {
                s16x8 bb = *(s16x8*)&s_k[nf * 16 + l16][ks * 32 + quad * 8];
                acc_s[nf] = __builtin_amdgcn_mfma_f32_16x16x32_bf16(a, bb, acc_s[nf], 0, 0, 0);
            }
        }

        int qg0 = qt * 64 + wave * 16 + quad * 4;
        float sc[4][4];
        #pragma unroll
        for (int nf = 0; nf < 4; nf++) {
            int jg = jt * 64 + nf * 16 + l16;
            #pragma unroll
            for (int r = 0; r < 4; r++) {
                float v = acc_s[nf][r] * 0.125f;
                if (jt == qt) {
                    int bound = mask_flag ? (qg0 + r) : (qg0 + r - 1);
                    if (jg > bound) v = -1e30f;
                }
                sc[nf][r] = v;
            }
        }
        float tmax[4];
        #pragma unroll
        for (int r = 0; r < 4; r++) {
            float t = fmaxf(fmaxf(sc[0][r], sc[1][r]), fmaxf(sc[2][r], sc[3][r]));
            #pragma unroll
            for (int o = 1; o < 16; o <<= 1) t = fmaxf(t, __shfl_xor(t, o));
            tmax[r] = t;
        }
        float p[4][4];
        #pragma unroll
        for (int r = 0; r < 4; r++) {
            float mnew = fmaxf(m_i[r], tmax[r]);
            float alpha = __expf(m_i[r] - mnew);
            float su = 0.f;
            #pragma unroll
            for (int nf = 0; nf < 4; nf++) { p[nf][r] = __expf(sc[nf][r] - mnew); su += p[nf][r]; }
            #pragma unroll
            for (int o = 1; o < 16; o <<= 1) su += __shfl_xor(su, o);
            l_i[r] = l_i[r] * alpha + su;
            m_i[r] = mnew;
            #pragma unroll
            for (int nf = 0; nf < 4; nf++) acc_o[nf][r] *= alpha;
        }
        #pragma unroll
        for (int nf = 0; nf < 4; nf++)
            #pragma unroll
            for (int r = 0; r < 4; r++)
                s_p[wave * 16 + quad * 4 + r][nf * 16 + l16] = f2b(p[nf][r]);

        #pragma unroll
        for (int ks = 0; ks < 2; ks++) {
            s16x8 a = *(s16x8*)&s_p[wave * 16 + l16][ks * 32 + quad * 8];
            #pragma unroll
            for (int nf = 0; nf < 4; nf++) {
                s16x8 bb = *(s16x8*)&s_vt[nf * 16 + l16][ks * 32 + quad * 8];
                acc_o[nf] = __builtin_amdgcn_mfma_f32_16x16x32_bf16(a, bb, acc_o[nf], 0, 0, 0);
            }
        }
    }

    float rm = rmask[b * 8 + h];
    int qrow = qt * 64 + wave * 16 + quad * 4;
    #pragma unroll
    for (int r = 0; r < 4; r++) {
        float scale = rm / l_i[r];
        u16* dst = ctx + (size_t)(b * SEQ + qrow + r) * DIM + h * DK;
        #pragma unroll
        for (int nf = 0; nf < 4; nf++)
            dst[nf * 16 + l16] = f2b(acc_o[nf][r] * scale);
    }
}

// ---- row q==0: uniform 1/SEQ over ALL keys; coalesced reads from vT ----
__global__ __launch_bounds__(256) void attn_row0(
    const u16* __restrict__ vT, const float* __restrict__ rmask, u16* __restrict__ ctx)
{
    int bh = blockIdx.x;
    int b = bh >> 3, h = bh & 7;
    int d = threadIdx.x >> 2, seg = threadIdx.x & 3;
    const u16* src = vT + ((size_t)bh * DK + d) * SEQ + seg * 128;
    float s = 0.f;
    for (int i = 0; i < 16; i++) {
        u16x8 v = *(const u16x8*)(src + i * 8);
        #pragma unroll
        for (int j = 0; j < 8; j++) s += b2f(v[j]);
    }
    s += __shfl_down(s, 1);
    s += __shfl_down(s, 2);
    if (seg == 0)
        ctx[(size_t)(b * SEQ) * DIM + h * DK + d] =
            f2b(s * (1.0f / (float)SEQ) * rmask[b * 8 + h]);
}

// ---- x = LN(x + y), also emit bf16 copy ----
__global__ __launch_bounds__(256) void add_ln_c(
    float* __restrict__ x, const float* __restrict__ y,
    const float* __restrict__ g, const float* __restrict__ bta,
    u16* __restrict__ out16)
{
    __shared__ float redA[4], redB[4];
    int row = blockIdx.x, tid = threadIdx.x;
    size_t base = (size_t)row * DIM;
    float t0 = x[base + tid] + y[base + tid];
    float t1 = x[base + tid + 256] + y[base + tid + 256];
    float s = t0 + t1, sq = t0 * t0 + t1 * t1;
    for (int o = 32; o > 0; o >>= 1) { s += __shfl_down(s, o, 64); sq += __shfl_down(sq, o, 64); }
    int lane = tid & 63, wid = tid >> 6;
    if (lane == 0) { redA[wid] = s; redB[wid] = sq; }
    __syncthreads();
    float S1 = redA[0] + redA[1] + redA[2] + redA[3];
    float S2 = redB[0] + redB[1] + redB[2] + redB[3];
    float mu = S1 * (1.0f / (float)DIM);
    float var = S2 * (1.0f / (float)DIM) - mu * mu;
    float rstd = rsqrtf(var + 1e-5f);
    float o0 = g[tid]       * (t0 - mu) * rstd + bta[tid];
    float o1 = g[tid + 256] * (t1 - mu) * rstd + bta[tid + 256];
    x[base + tid]       = o0;
    x[base + tid + 256] = o1;
    out16[base + tid]       = f2b(o0);
    out16[base + tid + 256] = f2b(o1);
}

// ---------------- host side ----------------
extern "C" void kernel_launch(void* const* d_in, const int* in_sizes, int n_in,
                              void* d_out, int out_size, void* d_ws, size_t ws_size,
                              hipStream_t stream) {
    const float* qe   = (const float*)d_in[0];
    const float* ie   = (const float*)d_in[1];
    const float* wq   = (const float*)d_in[2];
    const float* bq   = (const float*)d_in[3];
    const float* wv   = (const float*)d_in[4];
    const float* bv   = (const float*)d_in[5];
    const float* wo   = (const float*)d_in[6];
    const float* bo   = (const float*)d_in[7];
    const float* wg   = (const float*)d_in[8];
    const float* ln1g = (const float*)d_in[9];
    const float* ln1b = (const float*)d_in[10];
    const float* fw1  = (const float*)d_in[11];
    const float* fb1  = (const float*)d_in[12];
    const float* fw2  = (const float*)d_in[13];
    const float* fb2  = (const float*)d_in[14];
    const float* ln2g = (const float*)d_in[15];
    const float* ln2b = (const float*)d_in[16];

    const size_t RD = (size_t)NROWS * DIM;     // 4,194,304
    float* ws   = (float*)d_ws;
    float* xbuf = ws;
    float* ybuf = ws + RD;

    u16* b16    = (u16*)(ws + 2 * RD);
    u16* x16    = b16;                 b16 += RD;
    u16* y16    = b16;                 b16 += RD;
    u16* ctx16  = b16;                 b16 += RD;
    u16* qlin16 = b16;                 b16 += RD;
    u16* vbuf16 = b16;                 b16 += RD;
    u16* vT     = b16;                 b16 += RD;
    u16* hid    = ctx16;                        // 16 MiB overlay: ctx16+qlin16 (dead in FFN)
    float* proj = (float*)vbuf16;               // 16 MiB overlay: vbuf16+vT (dead after attn)
    u16* wqvT   = b16;                 b16 += 6 * (size_t)1024 * 512;
    u16* woT    = b16;                 b16 += 6 * (size_t)512 * 512;
    u16* fw1T   = b16;                 b16 += 2 * (size_t)DFF2 * 512;
    u16* fw2T   = b16;                 b16 += 2 * (size_t)512 * DFF2;
    float* rmask6 = (float*)b16;                // 6*128 floats

    const size_t nBytes = RD * sizeof(float);
    hipMemcpyAsync(xbuf, qe, nBytes, hipMemcpyDeviceToDevice, stream);
    hipMemcpyAsync(ybuf, ie, nBytes, hipMemcpyDeviceToDevice, stream);
    cast_f2b4<<<(int)(RD / 4 / 256), 256, 0, stream>>>(qe, x16, (int)(RD / 4));
    cast_f2b4<<<(int)(RD / 4 / 256), 256, 0, stream>>>(ie, y16, (int)(RD / 4));

    transpose_cast<<<dim3(16, 16, 6), 256, 0, stream>>>(wq, wqvT,             512, 512, 0, 1, (size_t)1024 * 512);
    transpose_cast<<<dim3(16, 16, 6), 256, 0, stream>>>(wv, wqvT + 512 * 512, 512, 512, 0, 1, (size_t)1024 * 512);
    transpose_cast<<<dim3(16, 16, 6), 256, 0, stream>>>(wo, woT,              512, 512, 0, 1, (size_t)512 * 512);
    transpose_cast<<<dim3(16, 64, 2), 256, 0, stream>>>(fw1, fw1T, 512, DFF2, 3, 2, (size_t)DFF2 * 512);
    transpose_cast<<<dim3(64, 16, 2), 256, 0, stream>>>(fw2, fw2T, DFF2, 512, 3, 2, (size_t)512 * DFF2);
    init_rmask6<<<3, 256, 0, stream>>>(rmask6);

    const int BIG = 1 << 30;
    auto run_block = [&](float* xr, u16* xq16, const u16* xv16, int l, int maskf, int pos) {
        size_t lD = (size_t)l * DIM;
        float* rm = rmask6 + l * 128;
        gemm2<1, 0, 0, 1><<<dim3(8, 64), 256, 0, stream>>>(
            xq16, xv16, wqvT + (size_t)l * 1024 * 512, bq + lD, bv + lD,
            qlin16, vbuf16, 512, 512, 512, 512, 512);
        transpose_v<<<dim3(8, 128), 256, 0, stream>>>(vbuf16, vT);
        router_kernel<<<NROWS / 4, 256, 0, stream>>>(qlin16, wg + (size_t)l * DIM * 6, rm);
        attn_flash<<<dim3(SEQ / 64, NH, BSZ), 256, 0, stream>>>(qlin16, vT, rm, ctx16, maskf);
        attn_row0<<<128, 256, 0, stream>>>(vT, rm, ctx16);
        gemm2<0, 0, 0, 0><<<dim3(4, 64), 256, 0, stream>>>(
            ctx16, ctx16, woT + (size_t)l * 512 * 512, bo + lD, nullptr,
            proj, nullptr, 512, 512, 512, 512, BIG);
        add_ln_c<<<NROWS, 256, 0, stream>>>(xr, proj, ln1g + lD, ln1b + lD, xq16);
        if (pos) {
            int slot = (l - 3) / 2;
            for (int c = 0; c < 2; c++) {
                gemm2<1, 1, 0, 0><<<dim3(8, 64), 256, 0, stream>>>(
                    xq16, xq16,
                    fw1T + (size_t)slot * DFF2 * 512 + (size_t)c * 1024 * 512,
                    fb1 + (size_t)l * DFF2 + c * 1024, nullptr,
                    hid, nullptr, 512, 512, 512, 1024, BIG);
                if (c == 0)
                    gemm2<0, 0, 0, 0><<<dim3(4, 64), 256, 0, stream>>>(
                        hid, hid, fw2T + (size_t)slot * 512 * DFF2,
                        fb2 + lD, nullptr, proj, nullptr, 1024, 1024, DFF2, 512, BIG);
                else
                    gemm2<0, 0, 1, 0><<<dim3(4, 64), 256, 0, stream>>>(
                        hid, hid, fw2T + (size_t)slot * 512 * DFF2 + 1024,
                        nullptr, nullptr, proj, nullptr, 1024, 1024, DFF2, 512, BIG);
            }
            add_ln_c<<<NROWS, 256, 0, stream>>>(xr, proj, ln2g + lD, ln2b + lD, xq16);
        }
    };

    run_block(ybuf, y16, y16, 0, 1, 0);
    run_block(ybuf, y16, y16, 1, 1, 0);
    run_block(xbuf, x16, x16, 2, 1, 0);
    run_block(xbuf, x16, y16, 3, 0, 1);
    run_block(xbuf, x16, x16, 4, 1, 0);
    run_block(xbuf, x16, y16, 5, 0, 1);

    hipMemcpyAsync(d_out, xbuf, nBytes, hipMemcpyDeviceToDevice, stream);
}